// Round 9
// baseline (495.589 us; speedup 1.0000x reference)
//
#include <hip/hip_runtime.h>
#include <hip/hip_bf16.h>
#include <hip/hip_cooperative_groups.h>
#include <math.h>

namespace cg = cooperative_groups;

#define NTILES 64
#define TPC 8
#define NCLUST 8
#define GRID_SZ 16
#define DIM 512
#define DHID 128
#define NTOK 2048
#define LN_EPS 1e-5f
#define TB 16             // tokens per chunk == MFMA M-tile
#define NCHUNK_MAX 192    // sum ceil(cnt/16) <= 128 + 60 < 192
#define GRIDB 1024        // cooperative grid: 4 blocks/CU x 256 CUs

typedef __attribute__((ext_vector_type(8))) short bf16x8;
typedef __attribute__((ext_vector_type(4))) float f32x4;

static __device__ __forceinline__ float fsign(float v) {
    return (v > 0.f) ? 1.f : ((v < 0.f) ? -1.f : 0.f);
}

static __device__ __forceinline__ bf16x8 cvt8(const float* p) {
    float4 a = *(const float4*)p;
    float4 b = *(const float4*)(p + 4);
    float e[8] = {a.x, a.y, a.z, a.w, b.x, b.y, b.z, b.w};
    bf16x8 v;
    #pragma unroll
    for (int i = 0; i < 8; ++i) {
        union { __hip_bfloat16 h; short s; } u;
        u.h = __float2bfloat16(e[i]);
        v[i] = u.s;
    }
    return v;
}

static __device__ __forceinline__ unsigned short bf16bits(float f) {
    union { __hip_bfloat16 h; unsigned short s; } u;
    u.h = __float2bfloat16(f);
    return u.s;
}

// in-wave self-routing: chunk id cb -> (t, base, m). false if no work.
static __device__ __forceinline__ bool route_chunk(const int* counts, int lane, int cb,
                                                   int& t, int& base, int& m) {
    int cnt_l = counts[lane];
    int nck = (cnt_l + TB - 1) / TB;
    int pre = nck;
    #pragma unroll
    for (int off = 1; off < 64; off <<= 1) {
        int u = __shfl_up(pre, off);
        if (lane >= off) pre += u;
    }
    int total = __shfl(pre, 63);
    pre -= nck;
    if (cb >= total) return false;
    unsigned long long msk = __ballot(cb >= pre && cb < pre + nck);
    t = (int)__builtin_ctzll(msk);
    base = (cb - __shfl(pre, t)) * TB;
    m = min(TB, __shfl(cnt_l, t) - base);
    return true;
}

// ---------------- fused cooperative kernel ----------------
__global__ __launch_bounds__(256, 4) void k_fused(const float* __restrict__ x,
                                                  const float* __restrict__ gamma,
                                                  const float* __restrict__ beta,
                                                  const float* __restrict__ Wd,
                                                  const float* __restrict__ sb,
                                                  const float* __restrict__ ss,
                                                  const float* __restrict__ Wu,
                                                  const float* __restrict__ scale,
                                                  float* __restrict__ out,
                                                  float* __restrict__ psum,
                                                  float* __restrict__ tile_sigs,
                                                  float* __restrict__ cluster_sigs,
                                                  int* __restrict__ counts,
                                                  int* __restrict__ list,
                                                  unsigned short* __restrict__ xn_b,
                                                  unsigned short* __restrict__ hs_b) {
    cg::grid_group grid = cg::this_grid();
    int bid = blockIdx.x;
    int tid = threadIdx.x;
    int lane = tid & 63;
    int wv = tid >> 6;

    // ===== phase 1: Wd column psums (blocks 0..511) || LayerNorm (blocks 512..1023)
    if (bid < 512) {
        int t = bid >> 3, part = bid & 7;
        const float* base = Wd + ((size_t)t * DHID + part * 16) * DIM;
        #pragma unroll
        for (int k2 = 0; k2 < 2; ++k2) {
            int d = tid + k2 * 256;
            float s = 0.f;
            #pragma unroll
            for (int j = 0; j < 16; ++j) s += base[(size_t)j * DIM + d];
            psum[((size_t)t * 8 + part) * DIM + d] = s;
        }
        if (bid == 0 && tid < NTILES) counts[tid] = 0;
    } else {
        int n = (bid - 512) * 4 + wv;
        const float* xr = x + (size_t)n * DIM;
        float v[8];
        float sum = 0.f;
        #pragma unroll
        for (int j = 0; j < 8; ++j) { float t = xr[lane + 64 * j]; v[j] = t; sum += t; }
        #pragma unroll
        for (int off = 32; off; off >>= 1) sum += __shfl_xor(sum, off);
        float mu = sum * (1.f / DIM);
        float sq = 0.f;
        #pragma unroll
        for (int j = 0; j < 8; ++j) { float t = v[j] - mu; sq += t * t; }
        #pragma unroll
        for (int off = 32; off; off >>= 1) sq += __shfl_xor(sq, off);
        float rs = rsqrtf(sq * (1.f / DIM) + LN_EPS);
        #pragma unroll
        for (int j = 0; j < 8; ++j) {
            int d = lane + 64 * j;
            float xv = (v[j] - mu) * rs * gamma[d] + beta[d];
            xn_b[(size_t)n * DIM + d] = bf16bits(xv);
        }
    }
    grid.sync();

    // ===== phase 2: tile_sigs + cluster_sigs (blocks 0..7)
    if (bid < NCLUST) {
        int c = bid;
        #pragma unroll
        for (int k2 = 0; k2 < 2; ++k2) {
            int d = tid + k2 * 256;
            float csum = 0.f;
            #pragma unroll
            for (int k = 0; k < TPC; ++k) {
                int t = c * TPC + k;
                float s = 0.f;
                #pragma unroll
                for (int p = 0; p < 8; ++p) s += psum[((size_t)t * 8 + p) * DIM + d];
                float sg = fsign(s);
                tile_sigs[(size_t)t * DIM + d] = sg;
                csum += sg;
            }
            cluster_sigs[(size_t)c * DIM + d] = fsign(csum);
        }
    }
    grid.sync();

    // ===== phase 3: routing (blocks 0..511, one token per wave)
    if (bid < 512) {
        int n = bid * 4 + wv;
        float sg[8];
        #pragma unroll
        for (int j = 0; j < 8; ++j) {
            unsigned short u = xn_b[(size_t)n * DIM + lane + 64 * j];
            // sign from bf16 bits: exact vs fp32 sign (RNE preserves sign; ±0 -> 0)
            sg[j] = ((u & 0x7fff) == 0) ? 0.f : ((u & 0x8000) ? -1.f : 1.f);
        }
        int best_c = 0; float best = -1e30f;
        for (int c = 0; c < NCLUST; ++c) {
            float s = 0.f;
            #pragma unroll
            for (int j = 0; j < 8; ++j) s += sg[j] * cluster_sigs[(size_t)c * DIM + lane + 64 * j];
            #pragma unroll
            for (int off = 32; off; off >>= 1) s += __shfl_xor(s, off);
            if (s > best) { best = s; best_c = c; }
        }
        int bt = best_c * TPC; float bts = -1e30f;
        for (int k = 0; k < TPC; ++k) {
            int t = best_c * TPC + k;
            float s = 0.f;
            #pragma unroll
            for (int j = 0; j < 8; ++j) s += sg[j] * tile_sigs[(size_t)t * DIM + lane + 64 * j];
            #pragma unroll
            for (int off = 32; off; off >>= 1) s += __shfl_xor(s, off);
            if (s > bts) { bts = s; bt = t; }
        }
        if (lane == 0) {
            int slot = atomicAdd(&counts[bt], 1);
            list[(size_t)bt * NTOK + slot] = n;
        }
    }
    grid.sync();

    // ===== phase 4: down-projection + spline (wave slot = chunk*8 + dh-tile)
    {
        int s = bid * 4 + wv;           // 0..4095
        int cb = s >> 3, dt = s & 7;
        int t, base, m;
        bool work = route_chunk(counts, lane, cb, t, base, m);
        if (work) {
            int mrow = lane & 15;
            int ko = (lane >> 4) * 8;
            int tokm = list[(size_t)t * NTOK + base + min(mrow, m - 1)];
            const unsigned short* xr = xn_b + (size_t)tokm * DIM;
            const float* wr = Wd + ((size_t)t * DHID + dt * 16 + mrow) * DIM;
            f32x4 acc = {0.f, 0.f, 0.f, 0.f};
            #pragma unroll 8
            for (int kk = 0; kk < 16; ++kk) {
                int d = kk * 32 + ko;
                bf16x8 a = *(const bf16x8*)(xr + d);
                acc = __builtin_amdgcn_mfma_f32_16x16x32_bf16(a, cvt8(wr + d), acc, 0, 0, 0);
            }
            int dh = dt * 16 + mrow;
            const float* sbt = sb + ((size_t)t * DHID + dh) * GRID_SZ;
            const float* sst = ss + ((size_t)t * DHID + dh) * GRID_SZ;
            #pragma unroll
            for (int r = 0; r < 4; ++r) {
                int tr = (lane >> 4) * 4 + r;
                float h = acc[r];
                float hn = 1.f / (1.f + expf(-h));
                float g = hn * (float)GRID_SZ;
                int idx = (int)g;
                idx = idx > GRID_SZ - 1 ? GRID_SZ - 1 : idx;
                float lp = g - (float)idx;
                float val = sbt[idx] + sst[idx] * lp;
                int tok_tr = __shfl(tokm, tr);
                if (tr < m) hs_b[(size_t)tok_tr * DHID + dh] = bf16bits(val);
            }
        }
    }
    grid.sync();

    // ===== phase 5: up-projection + residual (wave slot = chunk*8 + d-slice)
    {
        int s = bid * 4 + wv;
        int cb = s >> 3, ds = s & 7;
        int t, base, m;
        bool work = route_chunk(counts, lane, cb, t, base, m);
        if (work) {
            int mrow = lane & 15;
            int ko = (lane >> 4) * 8;
            int tokm = list[(size_t)t * NTOK + base + min(mrow, m - 1)];
            float sc_t = scale[t];
            const unsigned short* hr = hs_b + (size_t)tokm * DHID;
            bf16x8 a2[4];
            #pragma unroll
            for (int kk = 0; kk < 4; ++kk)
                a2[kk] = *(const bf16x8*)(hr + kk * 32 + ko);
            #pragma unroll 2
            for (int nt = 0; nt < 4; ++nt) {
                int d = ds * 64 + nt * 16 + mrow;
                const float* wr = Wu + ((size_t)t * DIM + d) * DHID;
                f32x4 acc = {0.f, 0.f, 0.f, 0.f};
                #pragma unroll
                for (int kk = 0; kk < 4; ++kk)
                    acc = __builtin_amdgcn_mfma_f32_16x16x32_bf16(a2[kk], cvt8(wr + kk * 32 + ko), acc, 0, 0, 0);
                #pragma unroll
                for (int r = 0; r < 4; ++r) {
                    int tr = (lane >> 4) * 4 + r;
                    int tok_tr = __shfl(tokm, tr);
                    if (tr < m) {
                        size_t o = (size_t)tok_tr * DIM + d;
                        out[o] = x[o] + acc[r] * sc_t;
                    }
                }
            }
        }
    }
}

// ---------------- fallback path (R8, proven) ----------------
__global__ __launch_bounds__(512) void k_sig_part(const float* __restrict__ Wd,
                                                  float* __restrict__ psum) {
    int t = blockIdx.x, part = blockIdx.y, tid = threadIdx.x;
    const float* base = Wd + ((size_t)t * DHID + part * 16) * DIM + tid;
    float s = 0.f;
    #pragma unroll
    for (int j = 0; j < 16; ++j) s += base[(size_t)j * DIM];
    psum[((size_t)t * 8 + part) * DIM + tid] = s;
}

__global__ __launch_bounds__(512) void k_csig(const float* __restrict__ psum,
                                              float* __restrict__ tile_sigs,
                                              float* __restrict__ cluster_sigs,
                                              int* __restrict__ counts) {
    int c = blockIdx.x, d = threadIdx.x;
    if (c == 0 && d < NTILES) counts[d] = 0;
    float csum = 0.f;
    #pragma unroll
    for (int k = 0; k < TPC; ++k) {
        int t = c * TPC + k;
        float s = 0.f;
        #pragma unroll
        for (int p = 0; p < 8; ++p) s += psum[((size_t)t * 8 + p) * DIM + d];
        float sg = fsign(s);
        tile_sigs[(size_t)t * DIM + d] = sg;
        csum += sg;
    }
    cluster_sigs[(size_t)c * DIM + d] = fsign(csum);
}

__global__ __launch_bounds__(256) void k_ln_route(const float* __restrict__ x,
                                                  const float* __restrict__ gamma,
                                                  const float* __restrict__ beta,
                                                  const float* __restrict__ tile_sigs,
                                                  const float* __restrict__ cluster_sigs,
                                                  unsigned short* __restrict__ xn_b,
                                                  int* __restrict__ counts,
                                                  int* __restrict__ list) {
    int n = blockIdx.x * 4 + (threadIdx.x >> 6);
    int lane = threadIdx.x & 63;
    const float* xr = x + (size_t)n * DIM;
    float v[8];
    float sum = 0.f;
    #pragma unroll
    for (int j = 0; j < 8; ++j) { float t = xr[lane + 64 * j]; v[j] = t; sum += t; }
    #pragma unroll
    for (int off = 32; off; off >>= 1) sum += __shfl_xor(sum, off);
    float mu = sum * (1.f / DIM);
    float sq = 0.f;
    #pragma unroll
    for (int j = 0; j < 8; ++j) { float t = v[j] - mu; sq += t * t; }
    #pragma unroll
    for (int off = 32; off; off >>= 1) sq += __shfl_xor(sq, off);
    float rs = rsqrtf(sq * (1.f / DIM) + LN_EPS);
    float sg[8];
    #pragma unroll
    for (int j = 0; j < 8; ++j) {
        int d = lane + 64 * j;
        float xv = (v[j] - mu) * rs * gamma[d] + beta[d];
        xn_b[(size_t)n * DIM + d] = bf16bits(xv);
        sg[j] = fsign(xv);
    }
    int best_c = 0; float best = -1e30f;
    for (int c = 0; c < NCLUST; ++c) {
        float s = 0.f;
        #pragma unroll
        for (int j = 0; j < 8; ++j) s += sg[j] * cluster_sigs[(size_t)c * DIM + lane + 64 * j];
        #pragma unroll
        for (int off = 32; off; off >>= 1) s += __shfl_xor(s, off);
        if (s > best) { best = s; best_c = c; }
    }
    int bt = best_c * TPC; float bts = -1e30f;
    for (int k = 0; k < TPC; ++k) {
        int t = best_c * TPC + k;
        float s = 0.f;
        #pragma unroll
        for (int j = 0; j < 8; ++j) s += sg[j] * tile_sigs[(size_t)t * DIM + lane + 64 * j];
        #pragma unroll
        for (int off = 32; off; off >>= 1) s += __shfl_xor(s, off);
        if (s > bts) { bts = s; bt = t; }
    }
    if (lane == 0) {
        int slot = atomicAdd(&counts[bt], 1);
        list[(size_t)bt * NTOK + slot] = n;
    }
}

__global__ __launch_bounds__(64, 2) void k_down(const unsigned short* __restrict__ xn_b,
                                                const float* __restrict__ Wd,
                                                const float* __restrict__ sb,
                                                const float* __restrict__ ss,
                                                const int* __restrict__ counts,
                                                const int* __restrict__ list,
                                                unsigned short* __restrict__ hs_b) {
    int lane = threadIdx.x;
    int cb = ((int)blockIdx.x & 7) * (NCHUNK_MAX / 8) + ((int)blockIdx.x >> 3);
    int t, base, m;
    if (!route_chunk(counts, lane, cb, t, base, m)) return;
    int dt = blockIdx.y;
    int mrow = lane & 15;
    int ko = (lane >> 4) * 8;
    int tokm = list[(size_t)t * NTOK + base + min(mrow, m - 1)];
    const unsigned short* xr = xn_b + (size_t)tokm * DIM;
    const float* wr = Wd + ((size_t)t * DHID + dt * 16 + mrow) * DIM;
    f32x4 acc = {0.f, 0.f, 0.f, 0.f};
    #pragma unroll 8
    for (int kk = 0; kk < 16; ++kk) {
        int d = kk * 32 + ko;
        bf16x8 a = *(const bf16x8*)(xr + d);
        acc = __builtin_amdgcn_mfma_f32_16x16x32_bf16(a, cvt8(wr + d), acc, 0, 0, 0);
    }
    int dh = dt * 16 + mrow;
    const float* sbt = sb + ((size_t)t * DHID + dh) * GRID_SZ;
    const float* sst = ss + ((size_t)t * DHID + dh) * GRID_SZ;
    #pragma unroll
    for (int r = 0; r < 4; ++r) {
        int tr = (lane >> 4) * 4 + r;
        float h = acc[r];
        float hn = 1.f / (1.f + expf(-h));
        float g = hn * (float)GRID_SZ;
        int idx = (int)g;
        idx = idx > GRID_SZ - 1 ? GRID_SZ - 1 : idx;
        float lp = g - (float)idx;
        float val = sbt[idx] + sst[idx] * lp;
        int tok_tr = __shfl(tokm, tr);
        if (tr < m) hs_b[(size_t)tok_tr * DHID + dh] = bf16bits(val);
    }
}

__global__ __launch_bounds__(64, 2) void k_up(const float* __restrict__ x,
                                              const unsigned short* __restrict__ hs_b,
                                              const float* __restrict__ Wu,
                                              const float* __restrict__ scale,
                                              const int* __restrict__ counts,
                                              const int* __restrict__ list,
                                              float* __restrict__ out) {
    int lane = threadIdx.x;
    int cb = ((int)blockIdx.x & 7) * (NCHUNK_MAX / 8) + ((int)blockIdx.x >> 3);
    int t, base, m;
    if (!route_chunk(counts, lane, cb, t, base, m)) return;
    int ds = blockIdx.y;
    int mrow = lane & 15;
    int ko = (lane >> 4) * 8;
    int tokm = list[(size_t)t * NTOK + base + min(mrow, m - 1)];
    float sc_t = scale[t];
    const unsigned short* hr = hs_b + (size_t)tokm * DHID;
    bf16x8 a2[4];
    #pragma unroll
    for (int kk = 0; kk < 4; ++kk)
        a2[kk] = *(const bf16x8*)(hr + kk * 32 + ko);
    #pragma unroll 2
    for (int nt = 0; nt < 4; ++nt) {
        int d = ds * 64 + nt * 16 + mrow;
        const float* wr = Wu + ((size_t)t * DIM + d) * DHID;
        f32x4 acc = {0.f, 0.f, 0.f, 0.f};
        #pragma unroll
        for (int kk = 0; kk < 4; ++kk)
            acc = __builtin_amdgcn_mfma_f32_16x16x32_bf16(a2[kk], cvt8(wr + kk * 32 + ko), acc, 0, 0, 0);
        #pragma unroll
        for (int r = 0; r < 4; ++r) {
            int tr = (lane >> 4) * 4 + r;
            int tok_tr = __shfl(tokm, tr);
            if (tr < m) {
                size_t o = (size_t)tok_tr * DIM + d;
                out[o] = x[o] + acc[r] * sc_t;
            }
        }
    }
}

extern "C" void kernel_launch(void* const* d_in, const int* in_sizes, int n_in,
                              void* d_out, int out_size, void* d_ws, size_t ws_size,
                              hipStream_t stream) {
    const float* x     = (const float*)d_in[0];
    const float* gamma = (const float*)d_in[1];
    const float* beta  = (const float*)d_in[2];
    const float* Wd    = (const float*)d_in[3];
    const float* sb    = (const float*)d_in[4];
    const float* ss    = (const float*)d_in[5];
    const float* Wu    = (const float*)d_in[6];
    const float* scale = (const float*)d_in[7];
    float* out = (float*)d_out;

    // workspace layout
    float* psum          = (float*)d_ws;                           // 64*8*512 f = 1 MB
    float* tile_sigs     = psum + (size_t)NTILES * 8 * DIM;        // 32K f
    float* cluster_sigs  = tile_sigs + NTILES * DIM;               // 4K f
    int*   counts        = (int*)(cluster_sigs + NCLUST * DIM);    // 64 ints
    int*   list          = counts + NTILES;                        // 128K ints
    unsigned short* xn_b = (unsigned short*)(list + (size_t)NTILES * NTOK);  // 1M u16
    unsigned short* hs_b = xn_b + (size_t)NTOK * DIM;              // 256K u16

    void* args[] = {(void*)&x, (void*)&gamma, (void*)&beta, (void*)&Wd, (void*)&sb,
                    (void*)&ss, (void*)&Wu, (void*)&scale, (void*)&out, (void*)&psum,
                    (void*)&tile_sigs, (void*)&cluster_sigs, (void*)&counts,
                    (void*)&list, (void*)&xn_b, (void*)&hs_b};
    hipError_t e = hipLaunchCooperativeKernel((const void*)k_fused, dim3(GRIDB), dim3(256),
                                              args, 0, stream);
    if (e != hipSuccess) {
        (void)hipGetLastError();   // clear error state; fall back to proven 5-kernel path
        k_sig_part<<<dim3(NTILES, 8), 512, 0, stream>>>(Wd, psum);
        k_csig<<<NCLUST, 512, 0, stream>>>(psum, tile_sigs, cluster_sigs, counts);
        k_ln_route<<<NTOK / 4, 256, 0, stream>>>(x, gamma, beta, tile_sigs, cluster_sigs, xn_b, counts, list);
        k_down<<<dim3(NCHUNK_MAX, 8), 64, 0, stream>>>(xn_b, Wd, sb, ss, counts, list, hs_b);
        k_up<<<dim3(NCHUNK_MAX, 8), 64, 0, stream>>>(x, hs_b, Wu, scale, counts, list, out);
    }
}

// Round 10
// 54.443 us; speedup vs baseline: 9.1030x; 9.1030x over previous
//
#include <hip/hip_runtime.h>
#include <hip/hip_bf16.h>
#include <math.h>

#define NTILES 64
#define TPC 8
#define NCLUST 8
#define GRID_SZ 16
#define DIM 512
#define DHID 128
#define NTOK 2048
#define LN_EPS 1e-5f
#define TB 16             // tokens per chunk == MFMA M-tile
#define NCHUNK_MAX 192    // sum ceil(cnt/16) <= 128 + 60 < 192 = 8*24

typedef __attribute__((ext_vector_type(8))) short bf16x8;
typedef __attribute__((ext_vector_type(4))) float f32x4;

static __device__ __forceinline__ float fsign(float v) {
    return (v > 0.f) ? 1.f : ((v < 0.f) ? -1.f : 0.f);
}

static __device__ __forceinline__ bf16x8 cvt8(const float* p) {
    float4 a = *(const float4*)p;
    float4 b = *(const float4*)(p + 4);
    float e[8] = {a.x, a.y, a.z, a.w, b.x, b.y, b.z, b.w};
    bf16x8 v;
    #pragma unroll
    for (int i = 0; i < 8; ++i) {
        union { __hip_bfloat16 h; short s; } u;
        u.h = __float2bfloat16(e[i]);
        v[i] = u.s;
    }
    return v;
}

static __device__ __forceinline__ unsigned short bf16bits(float f) {
    union { __hip_bfloat16 h; unsigned short s; } u;
    u.h = __float2bfloat16(f);
    return u.s;
}

// in-wave self-routing: chunk id cb -> (t, base, m). false if no work.
static __device__ __forceinline__ bool route_chunk(const int* counts, int lane, int cb,
                                                   int& t, int& base, int& m) {
    int cnt_l = counts[lane];
    int nck = (cnt_l + TB - 1) / TB;
    int pre = nck;
    #pragma unroll
    for (int off = 1; off < 64; off <<= 1) {
        int u = __shfl_up(pre, off);
        if (lane >= off) pre += u;
    }
    int total = __shfl(pre, 63);
    pre -= nck;
    if (cb >= total) return false;
    unsigned long long msk = __ballot(cb >= pre && cb < pre + nck);
    t = (int)__builtin_ctzll(msk);
    base = (cb - __shfl(pre, t)) * TB;
    m = min(TB, __shfl(cnt_l, t) - base);
    return true;
}

// K1: blocks 0..511 = Wd column psums; blocks 512..1023 = LayerNorm -> bf16 xn.
// Independent work co-dispatched (no cross-block dependency, no sync).
__global__ __launch_bounds__(256) void k_psum_ln(const float* __restrict__ x,
                                                 const float* __restrict__ gamma,
                                                 const float* __restrict__ beta,
                                                 const float* __restrict__ Wd,
                                                 float* __restrict__ psum,
                                                 unsigned short* __restrict__ xn_b,
                                                 int* __restrict__ counts) {
    int bid = blockIdx.x;
    int tid = threadIdx.x;
    if (bid < 512) {
        int t = bid >> 3, part = bid & 7;
        const float* basep = Wd + ((size_t)t * DHID + part * 16) * DIM;
        #pragma unroll
        for (int k2 = 0; k2 < 2; ++k2) {
            int d = tid + k2 * 256;
            float s = 0.f;
            #pragma unroll
            for (int j = 0; j < 16; ++j) s += basep[(size_t)j * DIM + d];
            psum[((size_t)t * 8 + part) * DIM + d] = s;
        }
        if (bid == 0 && tid < NTILES) counts[tid] = 0;
    } else {
        int n = (bid - 512) * 4 + (tid >> 6);
        int lane = tid & 63;
        const float* xr = x + (size_t)n * DIM;
        float v[8];
        float sum = 0.f;
        #pragma unroll
        for (int j = 0; j < 8; ++j) { float t = xr[lane + 64 * j]; v[j] = t; sum += t; }
        #pragma unroll
        for (int off = 32; off; off >>= 1) sum += __shfl_xor(sum, off);
        float mu = sum * (1.f / DIM);
        float sq = 0.f;
        #pragma unroll
        for (int j = 0; j < 8; ++j) { float t = v[j] - mu; sq += t * t; }
        #pragma unroll
        for (int off = 32; off; off >>= 1) sq += __shfl_xor(sq, off);
        float rs = rsqrtf(sq * (1.f / DIM) + LN_EPS);
        #pragma unroll
        for (int j = 0; j < 8; ++j) {
            int d = lane + 64 * j;
            float xv = (v[j] - mu) * rs * gamma[d] + beta[d];
            xn_b[(size_t)n * DIM + d] = bf16bits(xv);
        }
    }
}

// K2: tile_sigs + cluster_sigs. grid (NCLUST), 512 threads.
__global__ __launch_bounds__(512) void k_csig(const float* __restrict__ psum,
                                              float* __restrict__ tile_sigs,
                                              float* __restrict__ cluster_sigs) {
    int c = blockIdx.x, d = threadIdx.x;
    float csum = 0.f;
    #pragma unroll
    for (int k = 0; k < TPC; ++k) {
        int t = c * TPC + k;
        float s = 0.f;
        #pragma unroll
        for (int p = 0; p < 8; ++p) s += psum[((size_t)t * 8 + p) * DIM + d];
        float sg = fsign(s);
        tile_sigs[(size_t)t * DIM + d] = sg;
        csum += sg;
    }
    cluster_sigs[(size_t)c * DIM + d] = fsign(csum);
}

// K3: routing from bf16 xn sign bits (exact: RNE preserves sign, ±0 -> 0).
// 4 waves per block, one token per wave.
__global__ __launch_bounds__(256) void k_route(const unsigned short* __restrict__ xn_b,
                                               const float* __restrict__ tile_sigs,
                                               const float* __restrict__ cluster_sigs,
                                               int* __restrict__ counts,
                                               int* __restrict__ list) {
    int n = blockIdx.x * 4 + (threadIdx.x >> 6);
    int lane = threadIdx.x & 63;
    float sg[8];
    #pragma unroll
    for (int j = 0; j < 8; ++j) {
        unsigned short u = xn_b[(size_t)n * DIM + lane + 64 * j];
        sg[j] = ((u & 0x7fff) == 0) ? 0.f : ((u & 0x8000) ? -1.f : 1.f);
    }
    int best_c = 0; float best = -1e30f;
    for (int c = 0; c < NCLUST; ++c) {
        float s = 0.f;
        #pragma unroll
        for (int j = 0; j < 8; ++j) s += sg[j] * cluster_sigs[(size_t)c * DIM + lane + 64 * j];
        #pragma unroll
        for (int off = 32; off; off >>= 1) s += __shfl_xor(s, off);
        if (s > best) { best = s; best_c = c; }
    }
    int bt = best_c * TPC; float bts = -1e30f;
    for (int k = 0; k < TPC; ++k) {
        int t = best_c * TPC + k;
        float s = 0.f;
        #pragma unroll
        for (int j = 0; j < 8; ++j) s += sg[j] * tile_sigs[(size_t)t * DIM + lane + 64 * j];
        #pragma unroll
        for (int off = 32; off; off >>= 1) s += __shfl_xor(s, off);
        if (s > bts) { bts = s; bt = t; }
    }
    if (lane == 0) {
        int slot = atomicAdd(&counts[bt], 1);
        list[(size_t)bt * NTOK + slot] = n;
    }
}

// K4: fused down+spline+up. 192 blocks x 512 threads (8 waves, 1 chunk/block).
// wave w: down dh-tile w (16 MFMA, K=512) -> spline -> 4KB XOR-swizzled LDS hs
//         -> sync -> up d-slice w (4 n-tiles x 4 MFMA, K=128) + residual store.
__global__ __launch_bounds__(512, 2) void k_ffn(const float* __restrict__ x,
                                                const unsigned short* __restrict__ xn_b,
                                                const float* __restrict__ Wd,
                                                const float* __restrict__ sb,
                                                const float* __restrict__ ss,
                                                const float* __restrict__ Wu,
                                                const float* __restrict__ scale,
                                                const int* __restrict__ counts,
                                                const int* __restrict__ list,
                                                float* __restrict__ out) {
    int tid = threadIdx.x;
    int lane = tid & 63;
    int wv = tid >> 6;
    int cb = ((int)blockIdx.x & 7) * (NCHUNK_MAX / 8) + ((int)blockIdx.x >> 3);
    int t, base, m;
    if (!route_chunk(counts, lane, cb, t, base, m)) return;   // block-uniform exit

    __shared__ __align__(16) unsigned short hsl[TB * DHID];   // bf16, XOR-swizzled

    int mrow = lane & 15;
    int ko = (lane >> 4) * 8;
    int tokm = list[(size_t)t * NTOK + base + min(mrow, m - 1)];

    // ---- down: dh-tile wv ----
    const unsigned short* xr = xn_b + (size_t)tokm * DIM;
    const float* wr = Wd + ((size_t)t * DHID + wv * 16 + mrow) * DIM;
    f32x4 acc = {0.f, 0.f, 0.f, 0.f};
    #pragma unroll 8
    for (int kk = 0; kk < 16; ++kk) {
        int d = kk * 32 + ko;
        bf16x8 a = *(const bf16x8*)(xr + d);
        acc = __builtin_amdgcn_mfma_f32_16x16x32_bf16(a, cvt8(wr + d), acc, 0, 0, 0);
    }
    // spline on C fragments -> LDS (rows tr>=m hold duplicated last token: valid bytes)
    int dh = wv * 16 + mrow;
    const float* sbt = sb + ((size_t)t * DHID + dh) * GRID_SZ;
    const float* sst = ss + ((size_t)t * DHID + dh) * GRID_SZ;
    #pragma unroll
    for (int r = 0; r < 4; ++r) {
        int tr = (lane >> 4) * 4 + r;
        float h = acc[r];
        float hn = 1.f / (1.f + expf(-h));
        float g = hn * (float)GRID_SZ;
        int idx = (int)g;
        idx = idx > GRID_SZ - 1 ? GRID_SZ - 1 : idx;
        float lp = g - (float)idx;
        float val = sbt[idx] + sst[idx] * lp;
        hsl[(tr * DHID + dh) ^ ((tr & 7) << 3)] = bf16bits(val);
    }
    __syncthreads();

    // ---- up: d-slice wv ----
    float sc_t = scale[t];
    bf16x8 a2[4];
    #pragma unroll
    for (int kk = 0; kk < 4; ++kk)
        a2[kk] = *(const bf16x8*)&hsl[(mrow * DHID + kk * 32 + ko) ^ ((mrow & 7) << 3)];
    #pragma unroll 2
    for (int nt = 0; nt < 4; ++nt) {
        int d = wv * 64 + nt * 16 + mrow;
        const float* wru = Wu + ((size_t)t * DIM + d) * DHID;
        f32x4 au = {0.f, 0.f, 0.f, 0.f};
        #pragma unroll
        for (int kk = 0; kk < 4; ++kk)
            au = __builtin_amdgcn_mfma_f32_16x16x32_bf16(a2[kk], cvt8(wru + kk * 32 + ko), au, 0, 0, 0);
        #pragma unroll
        for (int r = 0; r < 4; ++r) {
            int tr = (lane >> 4) * 4 + r;
            int tok_tr = __shfl(tokm, tr);
            if (tr < m) {
                size_t o = (size_t)tok_tr * DIM + d;
                out[o] = x[o] + au[r] * sc_t;
            }
        }
    }
}

extern "C" void kernel_launch(void* const* d_in, const int* in_sizes, int n_in,
                              void* d_out, int out_size, void* d_ws, size_t ws_size,
                              hipStream_t stream) {
    const float* x     = (const float*)d_in[0];
    const float* gamma = (const float*)d_in[1];
    const float* beta  = (const float*)d_in[2];
    const float* Wd    = (const float*)d_in[3];
    const float* sb    = (const float*)d_in[4];
    const float* ss    = (const float*)d_in[5];
    const float* Wu    = (const float*)d_in[6];
    const float* scale = (const float*)d_in[7];
    float* out = (float*)d_out;

    // workspace layout
    float* psum          = (float*)d_ws;                           // 64*8*512 f = 1 MB
    float* tile_sigs     = psum + (size_t)NTILES * 8 * DIM;        // 32K f
    float* cluster_sigs  = tile_sigs + NTILES * DIM;               // 4K f
    int*   counts        = (int*)(cluster_sigs + NCLUST * DIM);    // 64 ints
    int*   list          = counts + NTILES;                        // 128K ints
    unsigned short* xn_b = (unsigned short*)(list + (size_t)NTILES * NTOK);  // 1M u16

    k_psum_ln<<<1024, 256, 0, stream>>>(x, gamma, beta, Wd, psum, xn_b, counts);
    k_csig<<<NCLUST, 512, 0, stream>>>(psum, tile_sigs, cluster_sigs);
    k_route<<<NTOK / 4, 256, 0, stream>>>(xn_b, tile_sigs, cluster_sigs, counts, list);
    k_ffn<<<NCHUNK_MAX, 512, 0, stream>>>(x, xn_b, Wd, sb, ss, Wu, scale, counts, list, out);
}

// Round 11
// 51.939 us; speedup vs baseline: 9.5417x; 1.0482x over previous
//
#include <hip/hip_runtime.h>
#include <hip/hip_bf16.h>
#include <math.h>

#define NTILES 64
#define TPC 8
#define NCLUST 8
#define GRID_SZ 16
#define DIM 512
#define DHID 128
#define NTOK 2048
#define LN_EPS 1e-5f
#define TB 16             // tokens per chunk == MFMA M-tile
#define NCHUNK_MAX 192    // sum ceil(cnt/16) <= 128 + 60 < 192 = 8*24

typedef __attribute__((ext_vector_type(8))) short bf16x8;
typedef __attribute__((ext_vector_type(4))) float f32x4;

static __device__ __forceinline__ float fsign(float v) {
    return (v > 0.f) ? 1.f : ((v < 0.f) ? -1.f : 0.f);
}

static __device__ __forceinline__ unsigned short bf16bits(float f) {
    union { __hip_bfloat16 h; unsigned short s; } u;
    u.h = __float2bfloat16(f);
    return u.s;
}

static __device__ __forceinline__ bf16x8 cvt8(const float* p) {
    float4 a = *(const float4*)p;
    float4 b = *(const float4*)(p + 4);
    float e[8] = {a.x, a.y, a.z, a.w, b.x, b.y, b.z, b.w};
    bf16x8 v;
    #pragma unroll
    for (int i = 0; i < 8; ++i) v[i] = (short)bf16bits(e[i]);
    return v;
}

// in-wave self-routing: chunk id cb -> (t, base, m). false if no work.
static __device__ __forceinline__ bool route_chunk(const int* counts, int lane, int cb,
                                                   int& t, int& base, int& m) {
    int cnt_l = counts[lane];
    int nck = (cnt_l + TB - 1) / TB;
    int pre = nck;
    #pragma unroll
    for (int off = 1; off < 64; off <<= 1) {
        int u = __shfl_up(pre, off);
        if (lane >= off) pre += u;
    }
    int total = __shfl(pre, 63);
    pre -= nck;
    if (cb >= total) return false;
    unsigned long long msk = __ballot(cb >= pre && cb < pre + nck);
    t = (int)__builtin_ctzll(msk);
    base = (cb - __shfl(pre, t)) * TB;
    m = min(TB, __shfl(cnt_l, t) - base);
    return true;
}

// K1: 1536 independent blocks, one dispatch (no cross-block deps):
//   0..511   : Wd column psums + bf16 Wd copy (reads each Wd element once)
//   512..1023: LayerNorm -> bf16 xn
//   1024..1535: streaming Wu -> bf16 copy
__global__ __launch_bounds__(256) void k_prep(const float* __restrict__ x,
                                              const float* __restrict__ gamma,
                                              const float* __restrict__ beta,
                                              const float* __restrict__ Wd,
                                              const float* __restrict__ Wu,
                                              float* __restrict__ psum,
                                              unsigned short* __restrict__ wd_b,
                                              unsigned short* __restrict__ wu_b,
                                              unsigned short* __restrict__ xn_b,
                                              int* __restrict__ counts) {
    int bid = blockIdx.x;
    int tid = threadIdx.x;
    if (bid < 512) {
        int t = bid >> 3, part = bid & 7;
        const float* basep = Wd + ((size_t)t * DHID + part * 16) * DIM;
        unsigned short* bb = wd_b + ((size_t)t * DHID + part * 16) * DIM;
        #pragma unroll
        for (int k2 = 0; k2 < 2; ++k2) {
            int d = tid + k2 * 256;
            float s = 0.f;
            #pragma unroll
            for (int j = 0; j < 16; ++j) {
                float v = basep[(size_t)j * DIM + d];
                s += v;
                bb[(size_t)j * DIM + d] = bf16bits(v);
            }
            psum[((size_t)t * 8 + part) * DIM + d] = s;
        }
        if (bid == 0 && tid < NTILES) counts[tid] = 0;
    } else if (bid < 1024) {
        int n = (bid - 512) * 4 + (tid >> 6);
        int lane = tid & 63;
        const float* xr = x + (size_t)n * DIM;
        float v[8];
        float sum = 0.f;
        #pragma unroll
        for (int j = 0; j < 8; ++j) { float t = xr[lane + 64 * j]; v[j] = t; sum += t; }
        #pragma unroll
        for (int off = 32; off; off >>= 1) sum += __shfl_xor(sum, off);
        float mu = sum * (1.f / DIM);
        float sq = 0.f;
        #pragma unroll
        for (int j = 0; j < 8; ++j) { float t = v[j] - mu; sq += t * t; }
        #pragma unroll
        for (int off = 32; off; off >>= 1) sq += __shfl_xor(sq, off);
        float rs = rsqrtf(sq * (1.f / DIM) + LN_EPS);
        #pragma unroll
        for (int j = 0; j < 8; ++j) {
            int d = lane + 64 * j;
            float xv = (v[j] - mu) * rs * gamma[d] + beta[d];
            xn_b[(size_t)n * DIM + d] = bf16bits(xv);
        }
    } else {
        // Wu streaming cvt: 512 blocks x 8192 floats
        size_t basei = (size_t)(bid - 1024) * 8192;
        #pragma unroll
        for (int k = 0; k < 4; ++k) {
            size_t off = basei + (size_t)tid * 8 + (size_t)k * 2048;
            bf16x8 v = cvt8(Wu + off);
            *(bf16x8*)(wu_b + off) = v;
        }
    }
}

// K2: tile_sigs + cluster_sigs. grid (NCLUST), 512 threads.
__global__ __launch_bounds__(512) void k_csig(const float* __restrict__ psum,
                                              float* __restrict__ tile_sigs,
                                              float* __restrict__ cluster_sigs) {
    int c = blockIdx.x, d = threadIdx.x;
    float csum = 0.f;
    #pragma unroll
    for (int k = 0; k < TPC; ++k) {
        int t = c * TPC + k;
        float s = 0.f;
        #pragma unroll
        for (int p = 0; p < 8; ++p) s += psum[((size_t)t * 8 + p) * DIM + d];
        float sg = fsign(s);
        tile_sigs[(size_t)t * DIM + d] = sg;
        csum += sg;
    }
    cluster_sigs[(size_t)c * DIM + d] = fsign(csum);
}

// K3: routing from bf16 xn sign bits (exact: RNE preserves sign, ±0 -> 0).
__global__ __launch_bounds__(256) void k_route(const unsigned short* __restrict__ xn_b,
                                               const float* __restrict__ tile_sigs,
                                               const float* __restrict__ cluster_sigs,
                                               int* __restrict__ counts,
                                               int* __restrict__ list) {
    int n = blockIdx.x * 4 + (threadIdx.x >> 6);
    int lane = threadIdx.x & 63;
    float sg[8];
    #pragma unroll
    for (int j = 0; j < 8; ++j) {
        unsigned short u = xn_b[(size_t)n * DIM + lane + 64 * j];
        sg[j] = ((u & 0x7fff) == 0) ? 0.f : ((u & 0x8000) ? -1.f : 1.f);
    }
    int best_c = 0; float best = -1e30f;
    for (int c = 0; c < NCLUST; ++c) {
        float s = 0.f;
        #pragma unroll
        for (int j = 0; j < 8; ++j) s += sg[j] * cluster_sigs[(size_t)c * DIM + lane + 64 * j];
        #pragma unroll
        for (int off = 32; off; off >>= 1) s += __shfl_xor(s, off);
        if (s > best) { best = s; best_c = c; }
    }
    int bt = best_c * TPC; float bts = -1e30f;
    for (int k = 0; k < TPC; ++k) {
        int t = best_c * TPC + k;
        float s = 0.f;
        #pragma unroll
        for (int j = 0; j < 8; ++j) s += sg[j] * tile_sigs[(size_t)t * DIM + lane + 64 * j];
        #pragma unroll
        for (int off = 32; off; off >>= 1) s += __shfl_xor(s, off);
        if (s > bts) { bts = s; bt = t; }
    }
    if (lane == 0) {
        int slot = atomicAdd(&counts[bt], 1);
        list[(size_t)bt * NTOK + slot] = n;
    }
}

// K4: fused down+spline+up with bf16 weights. 192 blocks x 512 threads.
// Inner loops are pure b128-load + MFMA (no cvt).
__global__ __launch_bounds__(512, 2) void k_ffn(const float* __restrict__ x,
                                                const unsigned short* __restrict__ xn_b,
                                                const unsigned short* __restrict__ wd_b,
                                                const float* __restrict__ sb,
                                                const float* __restrict__ ss,
                                                const unsigned short* __restrict__ wu_b,
                                                const float* __restrict__ scale,
                                                const int* __restrict__ counts,
                                                const int* __restrict__ list,
                                                float* __restrict__ out) {
    int tid = threadIdx.x;
    int lane = tid & 63;
    int wv = tid >> 6;
    int cb = ((int)blockIdx.x & 7) * (NCHUNK_MAX / 8) + ((int)blockIdx.x >> 3);
    int t, base, m;
    if (!route_chunk(counts, lane, cb, t, base, m)) return;   // block-uniform exit

    __shared__ __align__(16) unsigned short hsl[TB * DHID];   // bf16, XOR-swizzled

    int mrow = lane & 15;
    int ko = (lane >> 4) * 8;
    int tokm = list[(size_t)t * NTOK + base + min(mrow, m - 1)];

    // ---- down: dh-tile wv (16 MFMA, K=512) ----
    const unsigned short* xr = xn_b + (size_t)tokm * DIM;
    const unsigned short* wr = wd_b + ((size_t)t * DHID + wv * 16 + mrow) * DIM;
    f32x4 acc = {0.f, 0.f, 0.f, 0.f};
    #pragma unroll
    for (int kk = 0; kk < 16; ++kk) {
        int d = kk * 32 + ko;
        bf16x8 a = *(const bf16x8*)(xr + d);
        bf16x8 b = *(const bf16x8*)(wr + d);
        acc = __builtin_amdgcn_mfma_f32_16x16x32_bf16(a, b, acc, 0, 0, 0);
    }
    // spline on C fragments -> LDS (rows tr>=m hold duplicated last token: valid bytes)
    int dh = wv * 16 + mrow;
    const float* sbt = sb + ((size_t)t * DHID + dh) * GRID_SZ;
    const float* sst = ss + ((size_t)t * DHID + dh) * GRID_SZ;
    #pragma unroll
    for (int r = 0; r < 4; ++r) {
        int tr = (lane >> 4) * 4 + r;
        float h = acc[r];
        float hn = 1.f / (1.f + expf(-h));
        float g = hn * (float)GRID_SZ;
        int idx = (int)g;
        idx = idx > GRID_SZ - 1 ? GRID_SZ - 1 : idx;
        float lp = g - (float)idx;
        float val = sbt[idx] + sst[idx] * lp;
        hsl[(tr * DHID + dh) ^ ((tr & 7) << 3)] = bf16bits(val);
    }
    __syncthreads();

    // ---- up: d-slice wv (4 n-tiles x 4 MFMA, K=128) ----
    float sc_t = scale[t];
    bf16x8 a2[4];
    #pragma unroll
    for (int kk = 0; kk < 4; ++kk)
        a2[kk] = *(const bf16x8*)&hsl[(mrow * DHID + kk * 32 + ko) ^ ((mrow & 7) << 3)];
    #pragma unroll
    for (int nt = 0; nt < 4; ++nt) {
        int d = wv * 64 + nt * 16 + mrow;
        const unsigned short* wru = wu_b + ((size_t)t * DIM + d) * DHID;
        f32x4 au = {0.f, 0.f, 0.f, 0.f};
        #pragma unroll
        for (int kk = 0; kk < 4; ++kk) {
            bf16x8 b = *(const bf16x8*)(wru + kk * 32 + ko);
            au = __builtin_amdgcn_mfma_f32_16x16x32_bf16(a2[kk], b, au, 0, 0, 0);
        }
        #pragma unroll
        for (int r = 0; r < 4; ++r) {
            int tr = (lane >> 4) * 4 + r;
            int tok_tr = __shfl(tokm, tr);
            if (tr < m) {
                size_t o = (size_t)tok_tr * DIM + d;
                out[o] = x[o] + au[r] * sc_t;
            }
        }
    }
}

extern "C" void kernel_launch(void* const* d_in, const int* in_sizes, int n_in,
                              void* d_out, int out_size, void* d_ws, size_t ws_size,
                              hipStream_t stream) {
    const float* x     = (const float*)d_in[0];
    const float* gamma = (const float*)d_in[1];
    const float* beta  = (const float*)d_in[2];
    const float* Wd    = (const float*)d_in[3];
    const float* sb    = (const float*)d_in[4];
    const float* ss    = (const float*)d_in[5];
    const float* Wu    = (const float*)d_in[6];
    const float* scale = (const float*)d_in[7];
    float* out = (float*)d_out;

    // workspace layout
    float* psum          = (float*)d_ws;                           // 64*8*512 f = 1 MB
    float* tile_sigs     = psum + (size_t)NTILES * 8 * DIM;        // 32K f
    float* cluster_sigs  = tile_sigs + NTILES * DIM;               // 4K f
    int*   counts        = (int*)(cluster_sigs + NCLUST * DIM);    // 64 ints
    int*   list          = counts + NTILES;                        // 128K ints
    unsigned short* xn_b = (unsigned short*)(list + (size_t)NTILES * NTOK);  // 1M u16
    unsigned short* wd_b = xn_b + (size_t)NTOK * DIM;              // 4.19M u16
    unsigned short* wu_b = wd_b + (size_t)NTILES * DHID * DIM;     // 4.19M u16

    k_prep<<<1536, 256, 0, stream>>>(x, gamma, beta, Wd, Wu, psum, wd_b, wu_b, xn_b, counts);
    k_csig<<<NCLUST, 512, 0, stream>>>(psum, tile_sigs, cluster_sigs);
    k_route<<<NTOK / 4, 256, 0, stream>>>(xn_b, tile_sigs, cluster_sigs, counts, list);
    k_ffn<<<NCHUNK_MAX, 512, 0, stream>>>(x, xn_b, wd_b, sb, ss, wu_b, scale, counts, list, out);
}